// Round 2
// baseline (690.872 us; speedup 1.0000x reference)
//
#include <hip/hip_runtime.h>

#define THRESH   0.7f
#define BASEU    0x3F333334u   // bit pattern of smallest float > 0.7f
#define NBINS    2048          // top-level bins, (u-BASEU)>>12
#define NSUB     4096          // patterns per top-level bin (2^12)
#define NTHREADS 256
#define IPT4     4             // float4 per thread in k_main (32 elems/thread)
#define NSLOTS   64            // hashed accumulator slots (kills atomic serialization)
#define NBLK_FB  1024          // fallback kernels' grid (early-exit in common case)

struct Ws {
  double   slotSum[NSLOTS];
  unsigned slotCnt[NSLOTS];
  double   sum_eq;
  double   sum_lt;      // totals, filled by k_main finalizer
  double   prefix_sum;
  unsigned cnt_eq;
  unsigned cnt_lt;
  unsigned done;        // 1 => common case, out already written
  unsigned fin1, fin3, fin5;
  unsigned selBin, rank_r, prefix_cnt;
  unsigned Hcnt[NBINS];
  float    Hsum[NBINS];
  unsigned subCnt[NSUB];
  float    subSum[NSUB];
};

// t is exactly 0.0 or 1.0, so BCE collapses to a single log.
// Reference clamps each log term at -100 (torch BCELoss semantics).
__device__ __forceinline__ float bce_loss(float p, float t) {
  float x = (t > 0.5f) ? p : (1.0f - p);
  return -fmaxf(__logf(x), -100.0f);
}

// ---------------- K1: fused streaming pass (the hot kernel) ----------------
// One-shot grid: block b covers float4 indices [b*1024, (b+1)*1024).
// Each thread issues 4 pred-loads + 4 targ-loads back-to-back (8 in flight),
// one waitcnt per batch instead of per pair.
__global__ __launch_bounds__(NTHREADS) void k_main(
    const float4* __restrict__ p4, const float4* __restrict__ t4,
    float* __restrict__ out, Ws* __restrict__ ws, int n, int kidx) {
  const int nvec = n >> 2;
  const int base = blockIdx.x * (NTHREADS * IPT4) + threadIdx.x;

  float4 pr[IPT4], tr[IPT4];
  bool   ok[IPT4];
#pragma unroll
  for (int j = 0; j < IPT4; ++j) {
    int id = base + j * NTHREADS;
    ok[j] = (id < nvec);
    pr[j] = p4[ok[j] ? id : 0];
  }
#pragma unroll
  for (int j = 0; j < IPT4; ++j) {
    int id = base + j * NTHREADS;
    tr[j] = t4[ok[j] ? id : 0];
  }

  float s_lt = 0.f, s_eq = 0.f;
  unsigned c_lt = 0u, c_eq = 0u;
#pragma unroll
  for (int j = 0; j < IPT4; ++j) {
    if (!ok[j]) continue;
    float pa[4] = {pr[j].x, pr[j].y, pr[j].z, pr[j].w};
    float ta[4] = {tr[j].x, tr[j].y, tr[j].z, tr[j].w};
#pragma unroll
    for (int c = 0; c < 4; ++c) {
      float pv = pa[c];
      float loss = bce_loss(pv, ta[c]);
      if (pv < THRESH)       { c_lt++; s_lt += loss; }
      else if (pv == THRESH) { c_eq++; s_eq += loss; }
    }
  }
  // scalar tail (n % 4), handled by last block
  if (blockIdx.x == gridDim.x - 1) {
    int tail0 = nvec << 2;
    int i = tail0 + threadIdx.x;
    if (i < n) {
      float pv = __ldg((const float*)p4 + i);  // plain scalar load
      float loss = bce_loss(pv, __ldg((const float*)t4 + i));
      if (pv < THRESH)       { c_lt++; s_lt += loss; }
      else if (pv == THRESH) { c_eq++; s_eq += loss; }
    }
  }

  // wave(64) reduce
#pragma unroll
  for (int off = 32; off > 0; off >>= 1) {
    s_lt += __shfl_down(s_lt, off);
    s_eq += __shfl_down(s_eq, off);
    c_lt += __shfl_down(c_lt, off);
    c_eq += __shfl_down(c_eq, off);
  }
  __shared__ float    red_slt[4], red_seq[4];
  __shared__ unsigned red_clt[4], red_ceq[4];
  int wave = threadIdx.x >> 6;
  if ((threadIdx.x & 63) == 0) {
    red_slt[wave] = s_lt; red_seq[wave] = s_eq;
    red_clt[wave] = c_lt; red_ceq[wave] = c_eq;
  }
  __syncthreads();
  if (threadIdx.x == 0) {
    float    tslt = red_slt[0] + red_slt[1] + red_slt[2] + red_slt[3];
    float    tseq = red_seq[0] + red_seq[1] + red_seq[2] + red_seq[3];
    unsigned tclt = red_clt[0] + red_clt[1] + red_clt[2] + red_clt[3];
    unsigned tceq = red_ceq[0] + red_ceq[1] + red_ceq[2] + red_ceq[3];
    int slot = blockIdx.x & (NSLOTS - 1);
    atomicAdd(&ws->slotSum[slot], (double)tslt);
    atomicAdd(&ws->slotCnt[slot], tclt);
    if (tceq)        atomicAdd(&ws->cnt_eq, tceq);     // rare: usually skipped
    if (tseq != 0.f) atomicAdd(&ws->sum_eq, (double)tseq);
    __threadfence();
    unsigned prev = atomicAdd(&ws->fin1, 1u);
    if (prev == gridDim.x - 1) {   // last block finalizes
      __threadfence();
      double slt = 0.0; unsigned long long clt = 0;
      for (int i = 0; i < NSLOTS; ++i) {
        slt += atomicAdd(&ws->slotSum[i], 0.0);
        clt += atomicAdd(&ws->slotCnt[i], 0u);
      }
      unsigned ceq = atomicAdd(&ws->cnt_eq, 0u);
      ws->sum_lt = slt;              // totals for fallback kernels
      ws->cnt_lt = (unsigned)clt;
      // p_sorted[k] <= 0.7f  <=>  count(p <= 0.7f) >= k+1  => threshold = 0.7f
      if (clt + ceq > (unsigned long long)kidx) {
        out[0] = (float)(slt / (double)clt);
        ws->done = 1u;
      }
      // else done stays 0 (fallback kernels take over)
    }
  }
}

// ------- K2: fallback level-1 histogram over p>0.7 (early-exit normally) ----
__global__ __launch_bounds__(NTHREADS) void k_hist(
    const float* __restrict__ pred, const float* __restrict__ targ,
    Ws* __restrict__ ws, int n, int kidx, int nblocks) {
  if (ws->done) return;
  __shared__ unsigned hc[NBINS];
  __shared__ float    hs[NBINS];
  for (int i = threadIdx.x; i < NBINS; i += NTHREADS) { hc[i] = 0u; hs[i] = 0.f; }
  __syncthreads();

  int tid = blockIdx.x * blockDim.x + threadIdx.x;
  int stride = gridDim.x * blockDim.x;
  int nvec = n >> 2;
  const float4* p4 = (const float4*)pred;
  const float4* t4 = (const float4*)targ;
  for (int i = tid; i < nvec; i += stride) {
    float4 p = p4[i];
    float4 t = t4[i];
    float pa[4] = {p.x, p.y, p.z, p.w};
    float ta[4] = {t.x, t.y, t.z, t.w};
#pragma unroll
    for (int c = 0; c < 4; ++c) {
      float pv = pa[c];
      if (pv > THRESH) {
        unsigned b = (__float_as_uint(pv) - BASEU) >> 12;
        if (b > NBINS - 1) b = NBINS - 1;
        atomicAdd(&hc[b], 1u);
        atomicAdd(&hs[b], bce_loss(pv, ta[c]));
      }
    }
  }
  for (int i = (nvec << 2) + tid; i < n; i += stride) {
    float pv = pred[i];
    if (pv > THRESH) {
      unsigned b = (__float_as_uint(pv) - BASEU) >> 12;
      if (b > NBINS - 1) b = NBINS - 1;
      atomicAdd(&hc[b], 1u);
      atomicAdd(&hs[b], bce_loss(pv, targ[i]));
    }
  }
  __syncthreads();
  for (int i = threadIdx.x; i < NBINS; i += NTHREADS) {
    if (hc[i])        atomicAdd(&ws->Hcnt[i], hc[i]);
    if (hs[i] != 0.f) atomicAdd(&ws->Hsum[i], hs[i]);
  }
  __threadfence();
  if (threadIdx.x == 0) {
    unsigned prev = atomicAdd(&ws->fin3, 1u);
    if (prev == (unsigned)(nblocks - 1)) {
      __threadfence();
      unsigned long long cum  = (unsigned long long)ws->cnt_lt + atomicAdd(&ws->cnt_eq, 0u);
      double             csum = ws->sum_lt + ws->sum_eq;
      for (int b = 0; b < NBINS; ++b) {
        unsigned hcnt = atomicAdd(&ws->Hcnt[b], 0u);
        if (cum + hcnt > (unsigned long long)kidx) {
          ws->selBin     = (unsigned)b;
          ws->rank_r     = (unsigned)((unsigned long long)kidx - cum);
          ws->prefix_cnt = (unsigned)cum;
          ws->prefix_sum = csum;
          break;
        }
        cum  += hcnt;
        csum += (double)atomicAdd(&ws->Hsum[b], 0.f);
      }
    }
  }
}

// ------- K3: fallback level-2 (exact bit pattern) + final (early-exit) ------
__global__ __launch_bounds__(NTHREADS) void k_sub(
    const float* __restrict__ pred, const float* __restrict__ targ,
    float* __restrict__ out, Ws* __restrict__ ws, int n, int nblocks) {
  if (ws->done) return;
  unsigned base = BASEU + (ws->selBin << 12);
  __shared__ unsigned sc[NSUB];
  __shared__ float    ssm[NSUB];
  for (int i = threadIdx.x; i < NSUB; i += NTHREADS) { sc[i] = 0u; ssm[i] = 0.f; }
  __syncthreads();

  int tid = blockIdx.x * blockDim.x + threadIdx.x;
  int stride = gridDim.x * blockDim.x;
  int nvec = n >> 2;
  const float4* p4 = (const float4*)pred;
  const float4* t4 = (const float4*)targ;
  for (int i = tid; i < nvec; i += stride) {
    float4 p = p4[i];
    float4 t = t4[i];
    float pa[4] = {p.x, p.y, p.z, p.w};
    float ta[4] = {t.x, t.y, t.z, t.w};
#pragma unroll
    for (int c = 0; c < 4; ++c) {
      unsigned u = __float_as_uint(pa[c]);
      if (u >= base && u < base + NSUB) {
        atomicAdd(&sc[u - base], 1u);
        atomicAdd(&ssm[u - base], bce_loss(pa[c], ta[c]));
      }
    }
  }
  for (int i = (nvec << 2) + tid; i < n; i += stride) {
    unsigned u = __float_as_uint(pred[i]);
    if (u >= base && u < base + NSUB) {
      atomicAdd(&sc[u - base], 1u);
      atomicAdd(&ssm[u - base], bce_loss(pred[i], targ[i]));
    }
  }
  __syncthreads();
  for (int i = threadIdx.x; i < NSUB; i += NTHREADS) {
    if (sc[i])         atomicAdd(&ws->subCnt[i], sc[i]);
    if (ssm[i] != 0.f) atomicAdd(&ws->subSum[i], ssm[i]);
  }
  __threadfence();
  if (threadIdx.x == 0) {
    unsigned prev = atomicAdd(&ws->fin5, 1u);
    if (prev == (unsigned)(nblocks - 1)) {
      __threadfence();
      unsigned r = ws->rank_r;
      unsigned long long cum = 0;
      double csum = 0.0;
      for (int i = 0; i < NSUB; ++i) {
        unsigned c = atomicAdd(&ws->subCnt[i], 0u);
        if (cum + c > (unsigned long long)r) {
          unsigned long long cnt_final = (unsigned long long)ws->prefix_cnt + cum;
          double sum_final = ws->prefix_sum + csum;
          out[0] = (float)(sum_final / (double)cnt_final);
          break;
        }
        cum  += c;
        csum += (double)atomicAdd(&ws->subSum[i], 0.f);
      }
    }
  }
}

extern "C" void kernel_launch(void* const* d_in, const int* in_sizes, int n_in,
                              void* d_out, int out_size, void* d_ws, size_t ws_size,
                              hipStream_t stream) {
  const float* pred = (const float*)d_in[0];
  const float* targ = (const float*)d_in[1];
  float* out = (float*)d_out;
  Ws* ws = (Ws*)d_ws;
  int n = in_sizes[0];
  // min_kept = min(int(0.5*(n-1)), n-1); exact for positive n (trunc == floor)
  long long kll = (long long)(n - 1) / 2;
  if (kll > (long long)(n - 1)) kll = n - 1;
  int kidx = (int)kll;

  int nvec = n >> 2;
  int nblk_main = (nvec + NTHREADS * IPT4 - 1) / (NTHREADS * IPT4);
  if (nblk_main < 1) nblk_main = 1;

  hipMemsetAsync(d_ws, 0, sizeof(Ws), stream);
  k_main<<<nblk_main, NTHREADS, 0, stream>>>((const float4*)pred, (const float4*)targ,
                                             out, ws, n, kidx);
  k_hist<<<NBLK_FB, NTHREADS, 0, stream>>>(pred, targ, ws, n, kidx, NBLK_FB);
  k_sub <<<NBLK_FB, NTHREADS, 0, stream>>>(pred, targ, out, ws, n, NBLK_FB);
}

// Round 3
// 290.720 us; speedup vs baseline: 2.3764x; 2.3764x over previous
//
#include <hip/hip_runtime.h>

#define THRESH   0.7f
#define BASEU    0x3F333334u   // bit pattern of smallest float > 0.7f
#define NBINS    2048          // top-level bins, (u-BASEU)>>12
#define NSUB     4096          // patterns per top-level bin (2^12)
#define NTHREADS 256
#define IPT4     4             // float4 loads in flight per batch
#define NITER    4             // batches per thread -> 16 float4 = 64 elems... (4*4*4=64? no: 4 batches * 4 f4 * 4 elems = 64 elems) per thread
#define F4_PER_BLOCK (NTHREADS * IPT4 * NITER)   // 4096 float4 per block
#define MAXBLK   8192
#define NBLK_FB  1024          // fallback kernels' grid (early-exit in common case)

struct Blk { float sum_lt, sum_eq; unsigned cnt_lt, cnt_eq; };  // 16 B

struct Ws {
  Blk      blk[MAXBLK];
  double   sum_lt, sum_eq;     // totals (k_reduce)
  double   prefix_sum;
  unsigned cnt_lt, cnt_eq;
  unsigned done;               // 1 => common case, out written
  unsigned fin3, fin5;
  unsigned selBin, rank_r, prefix_cnt;
  unsigned Hcnt[NBINS];
  float    Hsum[NBINS];
  unsigned subCnt[NSUB];
  float    subSum[NSUB];
};

// t is exactly 0.0 or 1.0, so BCE collapses to a single log.
// Reference clamps each log term at -100 (torch BCELoss semantics).
__device__ __forceinline__ float bce_loss(float p, float t) {
  float x = (t > 0.5f) ? p : (1.0f - p);
  return -fmaxf(__logf(x), -100.0f);
}

// ---------------- K1: pure streaming pass (NO atomics, NO fences) ----------
__global__ __launch_bounds__(NTHREADS) void k_main(
    const float4* __restrict__ p4, const float4* __restrict__ t4,
    Ws* __restrict__ ws, int n) {
  const int nvec = n >> 2;
  const int start = blockIdx.x * F4_PER_BLOCK;

  float s_lt = 0.f, s_eq = 0.f;
  unsigned c_lt = 0u, c_eq = 0u;

  if (start + F4_PER_BLOCK <= nvec) {
    // fast path: fully in range, no guards
    for (int it = 0; it < NITER; ++it) {
      const int base = start + it * (NTHREADS * IPT4) + threadIdx.x;
      float4 pr[IPT4], tr[IPT4];
#pragma unroll
      for (int j = 0; j < IPT4; ++j) pr[j] = p4[base + j * NTHREADS];
#pragma unroll
      for (int j = 0; j < IPT4; ++j) tr[j] = t4[base + j * NTHREADS];
#pragma unroll
      for (int j = 0; j < IPT4; ++j) {
        float pa[4] = {pr[j].x, pr[j].y, pr[j].z, pr[j].w};
        float ta[4] = {tr[j].x, tr[j].y, tr[j].z, tr[j].w};
#pragma unroll
        for (int c = 0; c < 4; ++c) {
          float pv = pa[c];
          float loss = bce_loss(pv, ta[c]);
          if (pv < THRESH)       { c_lt++; s_lt += loss; }
          else if (pv == THRESH) { c_eq++; s_eq += loss; }
        }
      }
    }
  } else {
    // guarded path (last block only)
    for (int it = 0; it < NITER; ++it) {
      const int base = start + it * (NTHREADS * IPT4) + threadIdx.x;
#pragma unroll
      for (int j = 0; j < IPT4; ++j) {
        int id = base + j * NTHREADS;
        if (id < nvec) {
          float4 p = p4[id];
          float4 t = t4[id];
          float pa[4] = {p.x, p.y, p.z, p.w};
          float ta[4] = {t.x, t.y, t.z, t.w};
#pragma unroll
          for (int c = 0; c < 4; ++c) {
            float pv = pa[c];
            float loss = bce_loss(pv, ta[c]);
            if (pv < THRESH)       { c_lt++; s_lt += loss; }
            else if (pv == THRESH) { c_eq++; s_eq += loss; }
          }
        }
      }
    }
    // scalar tail (n % 4)
    int i = (nvec << 2) + threadIdx.x;
    if (blockIdx.x == gridDim.x - 1 && i < n) {
      float pv = ((const float*)p4)[i];
      float loss = bce_loss(pv, ((const float*)t4)[i]);
      if (pv < THRESH)       { c_lt++; s_lt += loss; }
      else if (pv == THRESH) { c_eq++; s_eq += loss; }
    }
  }

  // wave(64) reduce
#pragma unroll
  for (int off = 32; off > 0; off >>= 1) {
    s_lt += __shfl_down(s_lt, off);
    s_eq += __shfl_down(s_eq, off);
    c_lt += __shfl_down(c_lt, off);
    c_eq += __shfl_down(c_eq, off);
  }
  __shared__ float    red_slt[4], red_seq[4];
  __shared__ unsigned red_clt[4], red_ceq[4];
  int wave = threadIdx.x >> 6;
  if ((threadIdx.x & 63) == 0) {
    red_slt[wave] = s_lt; red_seq[wave] = s_eq;
    red_clt[wave] = c_lt; red_ceq[wave] = c_eq;
  }
  __syncthreads();
  if (threadIdx.x == 0) {
    Blk b;
    b.sum_lt = red_slt[0] + red_slt[1] + red_slt[2] + red_slt[3];
    b.sum_eq = red_seq[0] + red_seq[1] + red_seq[2] + red_seq[3];
    b.cnt_lt = red_clt[0] + red_clt[1] + red_clt[2] + red_clt[3];
    b.cnt_eq = red_ceq[0] + red_ceq[1] + red_ceq[2] + red_ceq[3];
    ws->blk[blockIdx.x] = b;   // plain 16-B store; end-of-kernel release
  }
}

// ---------------- K2: single-block cross-block reduce + decision -----------
__global__ __launch_bounds__(1024) void k_reduce(
    float* __restrict__ out, Ws* __restrict__ ws, int nblk, int kidx) {
  double s_lt = 0.0, s_eq = 0.0;
  unsigned long long c_lt = 0, c_eq = 0;
  for (int i = threadIdx.x; i < nblk; i += 1024) {
    Blk b = ws->blk[i];
    s_lt += (double)b.sum_lt; s_eq += (double)b.sum_eq;
    c_lt += b.cnt_lt;         c_eq += b.cnt_eq;
  }
#pragma unroll
  for (int off = 32; off > 0; off >>= 1) {
    s_lt += __shfl_down(s_lt, off);
    s_eq += __shfl_down(s_eq, off);
    c_lt += __shfl_down(c_lt, off);
    c_eq += __shfl_down(c_eq, off);
  }
  __shared__ double    rs[16], rq[16];
  __shared__ unsigned long long rc[16], re[16];
  int wave = threadIdx.x >> 6;
  if ((threadIdx.x & 63) == 0) { rs[wave] = s_lt; rq[wave] = s_eq; rc[wave] = c_lt; re[wave] = c_eq; }
  __syncthreads();
  if (threadIdx.x == 0) {
    double slt = 0.0, seq = 0.0; unsigned long long clt = 0, ceq = 0;
    for (int w = 0; w < 16; ++w) { slt += rs[w]; seq += rq[w]; clt += rc[w]; ceq += re[w]; }
    ws->sum_lt = slt; ws->sum_eq = seq;
    ws->cnt_lt = (unsigned)clt; ws->cnt_eq = (unsigned)ceq;
    // p_sorted[k] <= 0.7f  <=>  count(p <= 0.7f) >= k+1  => threshold = 0.7f
    if (clt + ceq > (unsigned long long)kidx) {
      out[0] = (float)(slt / (double)clt);
      ws->done = 1u;
    }
    // else done stays 0 (fallback kernels take over)
  }
}

// ------- K3: fallback level-1 histogram over p>0.7 (early-exit normally) ----
__global__ __launch_bounds__(NTHREADS) void k_hist(
    const float* __restrict__ pred, const float* __restrict__ targ,
    Ws* __restrict__ ws, int n, int kidx, int nblocks) {
  if (ws->done) return;
  __shared__ unsigned hc[NBINS];
  __shared__ float    hs[NBINS];
  for (int i = threadIdx.x; i < NBINS; i += NTHREADS) { hc[i] = 0u; hs[i] = 0.f; }
  __syncthreads();

  int tid = blockIdx.x * blockDim.x + threadIdx.x;
  int stride = gridDim.x * blockDim.x;
  int nvec = n >> 2;
  const float4* p4 = (const float4*)pred;
  const float4* t4 = (const float4*)targ;
  for (int i = tid; i < nvec; i += stride) {
    float4 p = p4[i];
    float4 t = t4[i];
    float pa[4] = {p.x, p.y, p.z, p.w};
    float ta[4] = {t.x, t.y, t.z, t.w};
#pragma unroll
    for (int c = 0; c < 4; ++c) {
      float pv = pa[c];
      if (pv > THRESH) {
        unsigned b = (__float_as_uint(pv) - BASEU) >> 12;
        if (b > NBINS - 1) b = NBINS - 1;
        atomicAdd(&hc[b], 1u);
        atomicAdd(&hs[b], bce_loss(pv, ta[c]));
      }
    }
  }
  for (int i = (nvec << 2) + tid; i < n; i += stride) {
    float pv = pred[i];
    if (pv > THRESH) {
      unsigned b = (__float_as_uint(pv) - BASEU) >> 12;
      if (b > NBINS - 1) b = NBINS - 1;
      atomicAdd(&hc[b], 1u);
      atomicAdd(&hs[b], bce_loss(pv, targ[i]));
    }
  }
  __syncthreads();
  for (int i = threadIdx.x; i < NBINS; i += NTHREADS) {
    if (hc[i])        atomicAdd(&ws->Hcnt[i], hc[i]);
    if (hs[i] != 0.f) atomicAdd(&ws->Hsum[i], hs[i]);
  }
  __threadfence();
  if (threadIdx.x == 0) {
    unsigned prev = atomicAdd(&ws->fin3, 1u);
    if (prev == (unsigned)(nblocks - 1)) {
      __threadfence();
      unsigned long long cum  = (unsigned long long)ws->cnt_lt + ws->cnt_eq;
      double             csum = ws->sum_lt + ws->sum_eq;
      for (int b = 0; b < NBINS; ++b) {
        unsigned hcnt = atomicAdd(&ws->Hcnt[b], 0u);
        if (cum + hcnt > (unsigned long long)kidx) {
          ws->selBin     = (unsigned)b;
          ws->rank_r     = (unsigned)((unsigned long long)kidx - cum);
          ws->prefix_cnt = (unsigned)cum;
          ws->prefix_sum = csum;
          break;
        }
        cum  += hcnt;
        csum += (double)atomicAdd(&ws->Hsum[b], 0.f);
      }
    }
  }
}

// ------- K4: fallback level-2 (exact bit pattern) + final (early-exit) ------
__global__ __launch_bounds__(NTHREADS) void k_sub(
    const float* __restrict__ pred, const float* __restrict__ targ,
    float* __restrict__ out, Ws* __restrict__ ws, int n, int nblocks) {
  if (ws->done) return;
  unsigned base = BASEU + (ws->selBin << 12);
  __shared__ unsigned sc[NSUB];
  __shared__ float    ssm[NSUB];
  for (int i = threadIdx.x; i < NSUB; i += NTHREADS) { sc[i] = 0u; ssm[i] = 0.f; }
  __syncthreads();

  int tid = blockIdx.x * blockDim.x + threadIdx.x;
  int stride = gridDim.x * blockDim.x;
  int nvec = n >> 2;
  const float4* p4 = (const float4*)pred;
  const float4* t4 = (const float4*)targ;
  for (int i = tid; i < nvec; i += stride) {
    float4 p = p4[i];
    float4 t = t4[i];
    float pa[4] = {p.x, p.y, p.z, p.w};
    float ta[4] = {t.x, t.y, t.z, t.w};
#pragma unroll
    for (int c = 0; c < 4; ++c) {
      unsigned u = __float_as_uint(pa[c]);
      if (u >= base && u < base + NSUB) {
        atomicAdd(&sc[u - base], 1u);
        atomicAdd(&ssm[u - base], bce_loss(pa[c], ta[c]));
      }
    }
  }
  for (int i = (nvec << 2) + tid; i < n; i += stride) {
    unsigned u = __float_as_uint(pred[i]);
    if (u >= base && u < base + NSUB) {
      atomicAdd(&sc[u - base], 1u);
      atomicAdd(&ssm[u - base], bce_loss(pred[i], targ[i]));
    }
  }
  __syncthreads();
  for (int i = threadIdx.x; i < NSUB; i += NTHREADS) {
    if (sc[i])         atomicAdd(&ws->subCnt[i], sc[i]);
    if (ssm[i] != 0.f) atomicAdd(&ws->subSum[i], ssm[i]);
  }
  __threadfence();
  if (threadIdx.x == 0) {
    unsigned prev = atomicAdd(&ws->fin5, 1u);
    if (prev == (unsigned)(nblocks - 1)) {
      __threadfence();
      unsigned r = ws->rank_r;
      unsigned long long cum = 0;
      double csum = 0.0;
      for (int i = 0; i < NSUB; ++i) {
        unsigned c = atomicAdd(&ws->subCnt[i], 0u);
        if (cum + c > (unsigned long long)r) {
          unsigned long long cnt_final = (unsigned long long)ws->prefix_cnt + cum;
          double sum_final = ws->prefix_sum + csum;
          out[0] = (float)(sum_final / (double)cnt_final);
          break;
        }
        cum  += c;
        csum += (double)atomicAdd(&ws->subSum[i], 0.f);
      }
    }
  }
}

extern "C" void kernel_launch(void* const* d_in, const int* in_sizes, int n_in,
                              void* d_out, int out_size, void* d_ws, size_t ws_size,
                              hipStream_t stream) {
  const float* pred = (const float*)d_in[0];
  const float* targ = (const float*)d_in[1];
  float* out = (float*)d_out;
  Ws* ws = (Ws*)d_ws;
  int n = in_sizes[0];
  // min_kept = min(int(0.5*(n-1)), n-1); exact for positive n (trunc == floor)
  long long kll = (long long)(n - 1) / 2;
  if (kll > (long long)(n - 1)) kll = n - 1;
  int kidx = (int)kll;

  int nvec = n >> 2;
  int nblk = (nvec + F4_PER_BLOCK - 1) / F4_PER_BLOCK;
  if (nblk < 1) nblk = 1;
  if (nblk > MAXBLK) nblk = MAXBLK;   // (n <= 134M elems; 32M here -> 2048)

  hipMemsetAsync(d_ws, 0, sizeof(Ws), stream);
  k_main  <<<nblk, NTHREADS, 0, stream>>>((const float4*)pred, (const float4*)targ, ws, n);
  k_reduce<<<1, 1024, 0, stream>>>(out, ws, nblk, kidx);
  k_hist  <<<NBLK_FB, NTHREADS, 0, stream>>>(pred, targ, ws, n, kidx, NBLK_FB);
  k_sub   <<<NBLK_FB, NTHREADS, 0, stream>>>(pred, targ, out, ws, n, NBLK_FB);
}

// Round 5
// 283.166 us; speedup vs baseline: 2.4398x; 1.0267x over previous
//
#include <hip/hip_runtime.h>

#define THRESH   0.7f
#define BASEU    0x3F333334u   // bit pattern of smallest float > 0.7f
#define NBINS    2048          // level-1 bins: (u-BASEU)>>12  (0.7..1.0 -> 1229 used)
#define NSUB     4096          // level-2: exact patterns within one level-1 bin
#define NTHREADS 256
#define F4_PER_CHUNK 4096      // per block-chunk: 4 batches x 1024 float4 (16384 elems)
#define MAXBLK   8192
#define NBLK_FB  1024          // fallback grid; must stay co-resident (spin syncs)

struct Blk { float sum_lt, sum_eq; unsigned cnt_lt, cnt_eq; };  // 16 B

struct Ws {
  Blk      blk[MAXBLK];
  double   sum_lt, sum_eq, prefix_sum;
  unsigned cnt_lt, cnt_eq;
  unsigned done;
  unsigned fin0, fin1, fin2, fin3;
  unsigned selBin, rank_r, prefix_cnt;
  unsigned Hcnt[NBINS];
  float    Hsum[NBINS];
  unsigned subCnt[NSUB];
  float    subSum[NSUB];
};

// t is exactly 0.0 or 1.0 -> BCE collapses to one log; torch clamps log at -100.
__device__ __forceinline__ float bce_loss(float p, float t) {
  float x = (t > 0.5f) ? p : (1.0f - p);
  return fminf(-__logf(x), 100.0f);
}

// =================== K1: pure streaming pass (no atomics) ===================
// Explicit 2-deep A/B software pipeline, 4+4 float4 per batch, p/t interleaved
// issue order. 64 data VGPRs in flight; __launch_bounds__(256,4) allows 128.
__global__ __launch_bounds__(NTHREADS, 4) void k_main(
    const float4* __restrict__ p4, const float4* __restrict__ t4,
    Ws* __restrict__ ws, int n, int nchunks) {
  const int nvec = n >> 2;
  float s_lt = 0.f, s_eq = 0.f;
  unsigned c_lt = 0u, c_eq = 0u;

#define CONSUME(PR, TR)                                                        \
  _Pragma("unroll") for (int j = 0; j < 4; ++j) {                              \
    float pa[4] = {PR[j].x, PR[j].y, PR[j].z, PR[j].w};                        \
    float ta[4] = {TR[j].x, TR[j].y, TR[j].z, TR[j].w};                        \
    _Pragma("unroll") for (int c = 0; c < 4; ++c) {                            \
      float pv = pa[c];                                                        \
      float x  = (ta[c] > 0.5f) ? pv : (1.0f - pv);                            \
      float l  = fminf(-__logf(x), 100.0f);                                    \
      bool lt  = (pv < THRESH);                                                \
      s_lt += lt ? l : 0.0f;                                                   \
      c_lt += lt ? 1u : 0u;                                                    \
      if (__any(pv == THRESH)) {  /* wave-uniform, ~never taken */             \
        bool eq = (pv == THRESH);                                              \
        c_eq += eq ? 1u : 0u;                                                  \
        s_eq += eq ? l : 0.0f;                                                 \
      }                                                                        \
    }                                                                          \
  }
#define LOADB(PR, TR, IT)                                                      \
  _Pragma("unroll") for (int j = 0; j < 4; ++j) {                              \
    PR[j] = pp[(IT) * 1024 + j * 256];                                         \
    TR[j] = tt[(IT) * 1024 + j * 256];                                         \
  }

  for (int chunk = blockIdx.x; chunk < nchunks; chunk += gridDim.x) {
    const int start = chunk * F4_PER_CHUNK;
    if (start + F4_PER_CHUNK <= nvec) {
      const float4* pp = p4 + start + threadIdx.x;
      const float4* tt = t4 + start + threadIdx.x;
      float4 pA[4], tA[4], pB[4], tB[4];
      LOADB(pA, tA, 0)
      LOADB(pB, tB, 1)
      CONSUME(pA, tA)
      LOADB(pA, tA, 2)
      CONSUME(pB, tB)
      LOADB(pB, tB, 3)
      CONSUME(pA, tA)
      CONSUME(pB, tB)
    } else {
      int lim = start + F4_PER_CHUNK; if (lim > nvec) lim = nvec;
      for (int f = start + threadIdx.x; f < lim; f += NTHREADS) {
        float4 p = p4[f];
        float4 t = t4[f];
        float pa[4] = {p.x, p.y, p.z, p.w};
        float ta[4] = {t.x, t.y, t.z, t.w};
#pragma unroll
        for (int c = 0; c < 4; ++c) {
          float pv = pa[c];
          float l = bce_loss(pv, ta[c]);
          if (pv < THRESH)       { c_lt++; s_lt += l; }
          else if (pv == THRESH) { c_eq++; s_eq += l; }
        }
      }
    }
  }
#undef LOADB
#undef CONSUME
  // scalar tail (n % 4)
  if (blockIdx.x == 0) {
    int i = (nvec << 2) + threadIdx.x;
    if (i < n) {
      float pv = ((const float*)p4)[i];
      float l = bce_loss(pv, ((const float*)t4)[i]);
      if (pv < THRESH)       { c_lt++; s_lt += l; }
      else if (pv == THRESH) { c_eq++; s_eq += l; }
    }
  }

  // wave(64) reduce then block reduce, plain 16-B store (no atomics, no fence)
#pragma unroll
  for (int off = 32; off > 0; off >>= 1) {
    s_lt += __shfl_down(s_lt, off);
    s_eq += __shfl_down(s_eq, off);
    c_lt += __shfl_down(c_lt, off);
    c_eq += __shfl_down(c_eq, off);
  }
  __shared__ float    red_slt[4], red_seq[4];
  __shared__ unsigned red_clt[4], red_ceq[4];
  int wave = threadIdx.x >> 6;
  if ((threadIdx.x & 63) == 0) {
    red_slt[wave] = s_lt; red_seq[wave] = s_eq;
    red_clt[wave] = c_lt; red_ceq[wave] = c_eq;
  }
  __syncthreads();
  if (threadIdx.x == 0) {
    Blk b;
    b.sum_lt = red_slt[0] + red_slt[1] + red_slt[2] + red_slt[3];
    b.sum_eq = red_seq[0] + red_seq[1] + red_seq[2] + red_seq[3];
    b.cnt_lt = red_clt[0] + red_clt[1] + red_clt[2] + red_clt[3];
    b.cnt_eq = red_ceq[0] + red_ceq[1] + red_ceq[2] + red_ceq[3];
    ws->blk[blockIdx.x] = b;
  }
}

// ======= K2: cross-block reduce + decision + fallback-counter init ==========
__global__ __launch_bounds__(1024) void k_decide(
    float* __restrict__ out, Ws* __restrict__ ws, int nblk, int kidx) {
  double s_lt = 0.0, s_eq = 0.0;
  unsigned long long c_lt = 0, c_eq = 0;
  for (int i = threadIdx.x; i < nblk; i += 1024) {
    Blk b = ws->blk[i];
    s_lt += (double)b.sum_lt; s_eq += (double)b.sum_eq;
    c_lt += b.cnt_lt;         c_eq += b.cnt_eq;
  }
#pragma unroll
  for (int off = 32; off > 0; off >>= 1) {
    s_lt += __shfl_down(s_lt, off);
    s_eq += __shfl_down(s_eq, off);
    c_lt += __shfl_down(c_lt, off);
    c_eq += __shfl_down(c_eq, off);
  }
  __shared__ double rs[16], rq[16];
  __shared__ unsigned long long rc[16], re[16];
  int wave = threadIdx.x >> 6;
  if ((threadIdx.x & 63) == 0) { rs[wave] = s_lt; rq[wave] = s_eq; rc[wave] = c_lt; re[wave] = c_eq; }
  __syncthreads();
  if (threadIdx.x == 0) {
    double slt = 0.0, seq = 0.0; unsigned long long clt = 0, ceq = 0;
    for (int w = 0; w < 16; ++w) { slt += rs[w]; seq += rq[w]; clt += rc[w]; ceq += re[w]; }
    ws->sum_lt = slt; ws->sum_eq = seq;
    ws->cnt_lt = (unsigned)clt; ws->cnt_eq = (unsigned)ceq;
    ws->fin0 = 0u; ws->fin1 = 0u; ws->fin2 = 0u; ws->fin3 = 0u;
    // p_sorted[k] <= 0.7f  <=>  count(p <= 0.7f) > k  => threshold = 0.7f
    if (clt + ceq > (unsigned long long)kidx) {
      out[0] = (float)(slt / (double)clt);
      ws->done = 1u;
    } else {
      ws->done = 0u;
    }
  }
}

// ================= K3: exact fallback, single kernel, spin-synced ===========
// Rare path (threshold > 0.7). NBLK_FB=1024 blocks, 32 KB LDS -> 5 blocks/CU
// -> 1280 co-resident >= 1024: spins cannot deadlock.
__device__ void gsync(unsigned* ctr, unsigned goal) {
  __syncthreads();
  if (threadIdx.x == 0) {
    __threadfence();
    atomicAdd(ctr, 1u);
    while (atomicAdd(ctr, 0u) < goal) __builtin_amdgcn_s_sleep(8);
  }
  __syncthreads();
  __threadfence();
}

__global__ __launch_bounds__(NTHREADS) void k_fallback(
    const float* __restrict__ pred, const float* __restrict__ targ,
    float* __restrict__ out, Ws* __restrict__ ws, int n, int kidx) {
  if (ws->done) return;   // common case: one load per block and out

  __shared__ union {
    struct { unsigned hc[NBINS]; float hs[NBINS]; } l1;
    struct { unsigned sc[NSUB];  float ss[NSUB];  } l2;
  } sh;

  const int gtid = blockIdx.x * NTHREADS + threadIdx.x;
  const int gstride = gridDim.x * NTHREADS;

  // ---- P0: zero global fallback arrays ----
  for (int i = gtid; i < NBINS; i += gstride) { ws->Hcnt[i] = 0u; ws->Hsum[i] = 0.f; }
  for (int i = gtid; i < NSUB;  i += gstride) { ws->subCnt[i] = 0u; ws->subSum[i] = 0.f; }
  gsync(&ws->fin0, gridDim.x);

  // ---- P1: level-1 histogram of p > 0.7 ----
  for (int i = threadIdx.x; i < NBINS; i += NTHREADS) { sh.l1.hc[i] = 0u; sh.l1.hs[i] = 0.f; }
  __syncthreads();
  for (int i = gtid; i < n; i += gstride) {
    float pv = pred[i];
    if (pv > THRESH) {
      unsigned b = (__float_as_uint(pv) - BASEU) >> 12;
      if (b > NBINS - 1) b = NBINS - 1;
      atomicAdd(&sh.l1.hc[b], 1u);
      atomicAdd(&sh.l1.hs[b], bce_loss(pv, targ[i]));
    }
  }
  __syncthreads();
  for (int i = threadIdx.x; i < NBINS; i += NTHREADS) {
    if (sh.l1.hc[i])        atomicAdd(&ws->Hcnt[i], sh.l1.hc[i]);
    if (sh.l1.hs[i] != 0.f) atomicAdd(&ws->Hsum[i], sh.l1.hs[i]);
  }
  gsync(&ws->fin1, gridDim.x);

  // ---- P2: block 0 selects the level-1 bin containing rank kidx ----
  if (blockIdx.x == 0 && threadIdx.x == 0) {
    unsigned long long cum = (unsigned long long)ws->cnt_lt + ws->cnt_eq;
    double csum = ws->sum_lt + ws->sum_eq;
    for (int b = 0; b < NBINS; ++b) {
      unsigned hcnt = atomicAdd(&ws->Hcnt[b], 0u);
      if (cum + hcnt > (unsigned long long)kidx) {
        atomicExch(&ws->selBin, (unsigned)b);
        atomicExch(&ws->rank_r, (unsigned)((unsigned long long)kidx - cum));
        atomicExch(&ws->prefix_cnt, (unsigned)cum);
        ws->prefix_sum = csum;
        break;
      }
      cum  += hcnt;
      csum += (double)atomicAdd(&ws->Hsum[b], 0.f);
    }
  }
  gsync(&ws->fin2, gridDim.x);

  // ---- P3: level-2 exact-pattern histogram within selected bin ----
  unsigned base = BASEU + (atomicAdd(&ws->selBin, 0u) << 12);
  for (int i = threadIdx.x; i < NSUB; i += NTHREADS) { sh.l2.sc[i] = 0u; sh.l2.ss[i] = 0.f; }
  __syncthreads();
  for (int i = gtid; i < n; i += gstride) {
    unsigned u = __float_as_uint(pred[i]);
    if (u >= base && u < base + NSUB) {
      atomicAdd(&sh.l2.sc[u - base], 1u);
      atomicAdd(&sh.l2.ss[u - base], bce_loss(pred[i], targ[i]));
    }
  }
  __syncthreads();
  for (int i = threadIdx.x; i < NSUB; i += NTHREADS) {
    if (sh.l2.sc[i])         atomicAdd(&ws->subCnt[i], sh.l2.sc[i]);
    if (sh.l2.ss[i] != 0.f)  atomicAdd(&ws->subSum[i], sh.l2.ss[i]);
  }
  gsync(&ws->fin3, gridDim.x);

  // ---- P4: block 0 finalizes ----
  if (blockIdx.x == 0 && threadIdx.x == 0) {
    unsigned r = atomicAdd(&ws->rank_r, 0u);
    unsigned long long cum = 0;
    double csum = 0.0;
    for (int i = 0; i < NSUB; ++i) {
      unsigned c = atomicAdd(&ws->subCnt[i], 0u);
      if (cum + c > (unsigned long long)r) {
        unsigned long long cnt_final = (unsigned long long)atomicAdd(&ws->prefix_cnt, 0u) + cum;
        double sum_final = ws->prefix_sum + csum;
        out[0] = (float)(sum_final / (double)cnt_final);
        break;
      }
      cum  += c;
      csum += (double)atomicAdd(&ws->subSum[i], 0.f);
    }
  }
}

extern "C" void kernel_launch(void* const* d_in, const int* in_sizes, int n_in,
                              void* d_out, int out_size, void* d_ws, size_t ws_size,
                              hipStream_t stream) {
  const float* pred = (const float*)d_in[0];
  const float* targ = (const float*)d_in[1];
  float* out = (float*)d_out;
  Ws* ws = (Ws*)d_ws;
  int n = in_sizes[0];
  // min_kept = min(int(0.5*(n-1)), n-1); trunc == floor for positive n
  long long kll = (long long)(n - 1) / 2;
  if (kll > (long long)(n - 1)) kll = n - 1;
  int kidx = (int)kll;

  int nvec = n >> 2;
  int nchunks = (nvec + F4_PER_CHUNK - 1) / F4_PER_CHUNK;
  if (nchunks < 1) nchunks = 1;
  int nblk = nchunks > MAXBLK ? MAXBLK : nchunks;

  k_main    <<<nblk, NTHREADS, 0, stream>>>((const float4*)pred, (const float4*)targ, ws, n, nchunks);
  k_decide  <<<1, 1024, 0, stream>>>(out, ws, nblk, kidx);
  k_fallback<<<NBLK_FB, NTHREADS, 0, stream>>>(pred, targ, out, ws, n, kidx);
}

// Round 6
// 275.459 us; speedup vs baseline: 2.5081x; 1.0280x over previous
//
#include <hip/hip_runtime.h>

#define THRESH   0.7f
#define BASEU    0x3F333334u   // bit pattern of smallest float > 0.7f
#define NBINS    2048          // level-1 bins: (u-BASEU)>>12  (0.7..1.0 -> 1229 used)
#define NSUB     4096          // level-2: exact patterns within one level-1 bin
#define NTHREADS 256
#define MAXBLK   8192
#define NBLK_FB  1024          // fallback grid; must stay co-resident (spin syncs)

struct Blk { float sum_lt, sum_eq; unsigned cnt_lt, cnt_eq; };  // 16 B

struct Ws {
  Blk      blk[MAXBLK];
  double   sum_lt, sum_eq, prefix_sum;
  unsigned cnt_lt, cnt_eq;
  unsigned done;
  unsigned fin0, fin1, fin2, fin3;
  unsigned selBin, rank_r, prefix_cnt;
  unsigned Hcnt[NBINS];
  float    Hsum[NBINS];
  unsigned subCnt[NSUB];
  float    subSum[NSUB];
};

// t is exactly 0.0 or 1.0 -> BCE collapses to one log; torch clamps log at -100.
__device__ __forceinline__ float bce_loss(float p, float t) {
  float x = (t > 0.5f) ? p : (1.0f - p);
  return fminf(-__logf(x), 100.0f);
}

// =================== K1: m13-shaped streaming pass ==========================
// Plain grid-stride, one float4-pair per iteration, zero branches in the body.
// Latency hiding via TLP (low VGPR -> 8 waves/SIMD), not ILP.
__global__ void k_main(
    const float4* __restrict__ p4, const float4* __restrict__ t4,
    Ws* __restrict__ ws, int n) {
  const int nvec = n >> 2;
  const int tid = blockIdx.x * NTHREADS + threadIdx.x;
  const int stride = gridDim.x * NTHREADS;

  float s_lt = 0.f, s_eq = 0.f;
  unsigned c_lt = 0u, c_eq = 0u;

  for (int i = tid; i < nvec; i += stride) {
    float4 p = p4[i];
    float4 t = t4[i];
    float pa[4] = {p.x, p.y, p.z, p.w};
    float ta[4] = {t.x, t.y, t.z, t.w};
#pragma unroll
    for (int c = 0; c < 4; ++c) {
      float pv = pa[c];
      float x  = (ta[c] > 0.5f) ? pv : (1.0f - pv);
      float l  = fminf(-__logf(x), 100.0f);
      bool lt  = (pv <  THRESH);
      bool eq  = (pv == THRESH);
      s_lt += lt ? l : 0.0f;          // branchless: cndmask + add
      c_lt += lt ? 1u : 0u;
      s_eq += eq ? l : 0.0f;
      c_eq += eq ? 1u : 0u;
    }
  }
  // scalar tail (n % 4)
  {
    int i = (nvec << 2) + tid;
    if (i < n) {
      float pv = ((const float*)p4)[i];
      float l = bce_loss(pv, ((const float*)t4)[i]);
      if (pv < THRESH)       { c_lt++; s_lt += l; }
      else if (pv == THRESH) { c_eq++; s_eq += l; }
    }
  }

  // wave(64) reduce then block reduce, plain 16-B store (no atomics, no fence)
#pragma unroll
  for (int off = 32; off > 0; off >>= 1) {
    s_lt += __shfl_down(s_lt, off);
    s_eq += __shfl_down(s_eq, off);
    c_lt += __shfl_down(c_lt, off);
    c_eq += __shfl_down(c_eq, off);
  }
  __shared__ float    red_slt[4], red_seq[4];
  __shared__ unsigned red_clt[4], red_ceq[4];
  int wave = threadIdx.x >> 6;
  if ((threadIdx.x & 63) == 0) {
    red_slt[wave] = s_lt; red_seq[wave] = s_eq;
    red_clt[wave] = c_lt; red_ceq[wave] = c_eq;
  }
  __syncthreads();
  if (threadIdx.x == 0) {
    Blk b;
    b.sum_lt = red_slt[0] + red_slt[1] + red_slt[2] + red_slt[3];
    b.sum_eq = red_seq[0] + red_seq[1] + red_seq[2] + red_seq[3];
    b.cnt_lt = red_clt[0] + red_clt[1] + red_clt[2] + red_clt[3];
    b.cnt_eq = red_ceq[0] + red_ceq[1] + red_ceq[2] + red_ceq[3];
    ws->blk[blockIdx.x] = b;
  }
}

// ======= K2: cross-block reduce + decision + fallback-counter init ==========
__global__ __launch_bounds__(1024) void k_decide(
    float* __restrict__ out, Ws* __restrict__ ws, int nblk, int kidx) {
  double s_lt = 0.0, s_eq = 0.0;
  unsigned long long c_lt = 0, c_eq = 0;
  for (int i = threadIdx.x; i < nblk; i += 1024) {
    Blk b = ws->blk[i];
    s_lt += (double)b.sum_lt; s_eq += (double)b.sum_eq;
    c_lt += b.cnt_lt;         c_eq += b.cnt_eq;
  }
#pragma unroll
  for (int off = 32; off > 0; off >>= 1) {
    s_lt += __shfl_down(s_lt, off);
    s_eq += __shfl_down(s_eq, off);
    c_lt += __shfl_down(c_lt, off);
    c_eq += __shfl_down(c_eq, off);
  }
  __shared__ double rs[16], rq[16];
  __shared__ unsigned long long rc[16], re[16];
  int wave = threadIdx.x >> 6;
  if ((threadIdx.x & 63) == 0) { rs[wave] = s_lt; rq[wave] = s_eq; rc[wave] = c_lt; re[wave] = c_eq; }
  __syncthreads();
  if (threadIdx.x == 0) {
    double slt = 0.0, seq = 0.0; unsigned long long clt = 0, ceq = 0;
    for (int w = 0; w < 16; ++w) { slt += rs[w]; seq += rq[w]; clt += rc[w]; ceq += re[w]; }
    ws->sum_lt = slt; ws->sum_eq = seq;
    ws->cnt_lt = (unsigned)clt; ws->cnt_eq = (unsigned)ceq;
    ws->fin0 = 0u; ws->fin1 = 0u; ws->fin2 = 0u; ws->fin3 = 0u;
    // p_sorted[k] <= 0.7f  <=>  count(p <= 0.7f) > k  => threshold = 0.7f
    if (clt + ceq > (unsigned long long)kidx) {
      out[0] = (float)(slt / (double)clt);
      ws->done = 1u;
    } else {
      ws->done = 0u;
    }
  }
}

// ================= K3: exact fallback, single kernel, spin-synced ===========
// Rare path (threshold > 0.7). NBLK_FB=1024 blocks, 32 KB LDS -> 5 blocks/CU
// -> 1280 co-resident >= 1024: spins cannot deadlock.
__device__ void gsync(unsigned* ctr, unsigned goal) {
  __syncthreads();
  if (threadIdx.x == 0) {
    __threadfence();
    atomicAdd(ctr, 1u);
    while (atomicAdd(ctr, 0u) < goal) __builtin_amdgcn_s_sleep(8);
  }
  __syncthreads();
  __threadfence();
}

__global__ __launch_bounds__(NTHREADS) void k_fallback(
    const float* __restrict__ pred, const float* __restrict__ targ,
    float* __restrict__ out, Ws* __restrict__ ws, int n, int kidx) {
  if (ws->done) return;   // common case: one load per block and out

  __shared__ union {
    struct { unsigned hc[NBINS]; float hs[NBINS]; } l1;
    struct { unsigned sc[NSUB];  float ss[NSUB];  } l2;
  } sh;

  const int gtid = blockIdx.x * NTHREADS + threadIdx.x;
  const int gstride = gridDim.x * NTHREADS;

  // ---- P0: zero global fallback arrays ----
  for (int i = gtid; i < NBINS; i += gstride) { ws->Hcnt[i] = 0u; ws->Hsum[i] = 0.f; }
  for (int i = gtid; i < NSUB;  i += gstride) { ws->subCnt[i] = 0u; ws->subSum[i] = 0.f; }
  gsync(&ws->fin0, gridDim.x);

  // ---- P1: level-1 histogram of p > 0.7 ----
  for (int i = threadIdx.x; i < NBINS; i += NTHREADS) { sh.l1.hc[i] = 0u; sh.l1.hs[i] = 0.f; }
  __syncthreads();
  for (int i = gtid; i < n; i += gstride) {
    float pv = pred[i];
    if (pv > THRESH) {
      unsigned b = (__float_as_uint(pv) - BASEU) >> 12;
      if (b > NBINS - 1) b = NBINS - 1;
      atomicAdd(&sh.l1.hc[b], 1u);
      atomicAdd(&sh.l1.hs[b], bce_loss(pv, targ[i]));
    }
  }
  __syncthreads();
  for (int i = threadIdx.x; i < NBINS; i += NTHREADS) {
    if (sh.l1.hc[i])        atomicAdd(&ws->Hcnt[i], sh.l1.hc[i]);
    if (sh.l1.hs[i] != 0.f) atomicAdd(&ws->Hsum[i], sh.l1.hs[i]);
  }
  gsync(&ws->fin1, gridDim.x);

  // ---- P2: block 0 selects the level-1 bin containing rank kidx ----
  if (blockIdx.x == 0 && threadIdx.x == 0) {
    unsigned long long cum = (unsigned long long)ws->cnt_lt + ws->cnt_eq;
    double csum = ws->sum_lt + ws->sum_eq;
    for (int b = 0; b < NBINS; ++b) {
      unsigned hcnt = atomicAdd(&ws->Hcnt[b], 0u);
      if (cum + hcnt > (unsigned long long)kidx) {
        atomicExch(&ws->selBin, (unsigned)b);
        atomicExch(&ws->rank_r, (unsigned)((unsigned long long)kidx - cum));
        atomicExch(&ws->prefix_cnt, (unsigned)cum);
        ws->prefix_sum = csum;
        break;
      }
      cum  += hcnt;
      csum += (double)atomicAdd(&ws->Hsum[b], 0.f);
    }
  }
  gsync(&ws->fin2, gridDim.x);

  // ---- P3: level-2 exact-pattern histogram within selected bin ----
  unsigned base = BASEU + (atomicAdd(&ws->selBin, 0u) << 12);
  for (int i = threadIdx.x; i < NSUB; i += NTHREADS) { sh.l2.sc[i] = 0u; sh.l2.ss[i] = 0.f; }
  __syncthreads();
  for (int i = gtid; i < n; i += gstride) {
    unsigned u = __float_as_uint(pred[i]);
    if (u >= base && u < base + NSUB) {
      atomicAdd(&sh.l2.sc[u - base], 1u);
      atomicAdd(&sh.l2.ss[u - base], bce_loss(pred[i], targ[i]));
    }
  }
  __syncthreads();
  for (int i = threadIdx.x; i < NSUB; i += NTHREADS) {
    if (sh.l2.sc[i])         atomicAdd(&ws->subCnt[i], sh.l2.sc[i]);
    if (sh.l2.ss[i] != 0.f)  atomicAdd(&ws->subSum[i], sh.l2.ss[i]);
  }
  gsync(&ws->fin3, gridDim.x);

  // ---- P4: block 0 finalizes ----
  if (blockIdx.x == 0 && threadIdx.x == 0) {
    unsigned r = atomicAdd(&ws->rank_r, 0u);
    unsigned long long cum = 0;
    double csum = 0.0;
    for (int i = 0; i < NSUB; ++i) {
      unsigned c = atomicAdd(&ws->subCnt[i], 0u);
      if (cum + c > (unsigned long long)r) {
        unsigned long long cnt_final = (unsigned long long)atomicAdd(&ws->prefix_cnt, 0u) + cum;
        double sum_final = ws->prefix_sum + csum;
        out[0] = (float)(sum_final / (double)cnt_final);
        break;
      }
      cum  += c;
      csum += (double)atomicAdd(&ws->subSum[i], 0.f);
    }
  }
}

extern "C" void kernel_launch(void* const* d_in, const int* in_sizes, int n_in,
                              void* d_out, int out_size, void* d_ws, size_t ws_size,
                              hipStream_t stream) {
  const float* pred = (const float*)d_in[0];
  const float* targ = (const float*)d_in[1];
  float* out = (float*)d_out;
  Ws* ws = (Ws*)d_ws;
  int n = in_sizes[0];
  // min_kept = min(int(0.5*(n-1)), n-1); trunc == floor for positive n
  long long kll = (long long)(n - 1) / 2;
  if (kll > (long long)(n - 1)) kll = n - 1;
  int kidx = (int)kll;

  int nvec = n >> 2;
  int nblk = (nvec + NTHREADS - 1) / NTHREADS;
  if (nblk > MAXBLK) nblk = MAXBLK;
  if (nblk < 1) nblk = 1;

  k_main    <<<nblk, NTHREADS, 0, stream>>>((const float4*)pred, (const float4*)targ, ws, n);
  k_decide  <<<1, 1024, 0, stream>>>(out, ws, nblk, kidx);
  k_fallback<<<NBLK_FB, NTHREADS, 0, stream>>>(pred, targ, out, ws, n, kidx);
}